// Round 7
// baseline (93.393 us; speedup 1.0000x reference)
//
#include <hip/hip_runtime.h>
#include <hip/hip_bf16.h>
#include <stdint.h>

// NT-Xent loss, B=4096, D=256, T=0.5, eps=1e-8.
// loss_r = log(sum_{c!=r} exp(2*dot(zn_r,zn_c))) - 2*dot(zin_r, zjn_r); out = mean.
// zn_s = zn * sqrt(2*log2e) stored bf16 -> MFMA acc = 2*log2e*dot -> exp2(acc) direct.
// Diagonal accumulated unconditionally; subtracted in k_loss via exp2(diag).
//
// LESSONS:
//  R2/R4: launch_bounds VGPR cap ~= 256/arg2; arg2=4 -> 64 VGPR -> afrag spills -> 4-6x.
//  R6: no-LDS B loads can't pipeline in 128 VGPR -> L2-latency-bound.
//  R1..R6 all ran 8 waves/CU (2/SIMD) -> TLP-starved.
// R7: 512-thr blocks (8 waves), afrag[4][8] per wave (64 rows), dbuf LDS 2x32KB,
//     grid 512 -> 2 blocks/CU * 8 waves = 16 waves/CU = 4/SIMD.

#define BROWS 4096
#define DIM   256
#define N2    8192

typedef __attribute__((ext_vector_type(4))) float          f32x4;
typedef __attribute__((ext_vector_type(8))) short          s16x8;
typedef __attribute__((ext_vector_type(4))) unsigned short u16x4;

#define S_EXP  1.6986436597467051f   /* sqrt(2*log2(e)) */
#define LN2    0.6931471805599453f

__device__ inline unsigned short f2bf(float f) {
    uint32_t b = __float_as_uint(f);
    b += 0x7fffu + ((b >> 16) & 1u);   // RNE
    return (unsigned short)(b >> 16);
}
__device__ inline float bf2f(unsigned short u) {
    return __uint_as_float(((uint32_t)u) << 16);
}

__device__ inline void gload_lds16(const void* g, void* l) {
    __builtin_amdgcn_global_load_lds(
        (const __attribute__((address_space(1))) uint32_t*)g,
        (__attribute__((address_space(3))) uint32_t*)l, 16, 0, 0);
}

__device__ inline float wave_reduce(float v) {
    #pragma unroll
    for (int m = 1; m < 64; m <<= 1) v += __shfl_xor(v, m);
    return v;
}

// ---- K1: fused normalize (both views) + positive-pair exponent + diag self-dot ----
__global__ __launch_bounds__(256) void k_norm_pos(const float* __restrict__ zi,
                                                  const float* __restrict__ zj,
                                                  unsigned short* __restrict__ zn,
                                                  float* __restrict__ diag,
                                                  float* __restrict__ posv,
                                                  unsigned int* __restrict__ counter) {
    if (blockIdx.x == 0 && threadIdx.x == 0) *counter = 0u;
    int i    = blockIdx.x * 4 + (threadIdx.x >> 6);
    int lane = threadIdx.x & 63;
    f32x4 a = *(const f32x4*)(zi + (size_t)i * DIM + lane * 4);
    f32x4 b = *(const f32x4*)(zj + (size_t)i * DIM + lane * 4);
    float ssa = a[0]*a[0] + a[1]*a[1] + a[2]*a[2] + a[3]*a[3];
    float ssb = b[0]*b[0] + b[1]*b[1] + b[2]*b[2] + b[3]*b[3];
    float dab = a[0]*b[0] + a[1]*b[1] + a[2]*b[2] + a[3]*b[3];
    ssa = wave_reduce(ssa);
    ssb = wave_reduce(ssb);
    dab = wave_reduce(dab);
    float na = 1.0f / fmaxf(sqrtf(ssa), 1e-8f);
    float nb = 1.0f / fmaxf(sqrtf(ssb), 1e-8f);
    if (lane == 0) posv[i] = 2.0f * dab * na * nb;   // natural-log exponent of pos pair

    float sa = na * S_EXP, sb = nb * S_EXP;
    u16x4 oa, ob;
    float da = 0.0f, db = 0.0f;
    #pragma unroll
    for (int k = 0; k < 4; ++k) {
        unsigned short ua = f2bf(a[k] * sa);
        unsigned short ub = f2bf(b[k] * sb);
        oa[k] = ua; ob[k] = ub;
        float fa = bf2f(ua), fb = bf2f(ub);
        da += fa * fa; db += fb * fb;
    }
    *(u16x4*)(zn + (size_t)i * DIM + lane * 4)           = oa;
    *(u16x4*)(zn + (size_t)(i + BROWS) * DIM + lane * 4) = ob;
    da = wave_reduce(da);
    db = wave_reduce(db);
    if (lane == 0) { diag[i] = da; diag[i + BROWS] = db; }
}

// ---- K2: fused sim GEMM + exp2 + row-sum (diagonal NOT masked) ----
// 512 thr = 8 waves; block tile 512 rows x 256 cols; grid = 16*32 = 512.
// Wave owns 64 rows (afrag[4][8], 64 VGPR). B dbuf in LDS 2x32KB, staged with
// global_load_lds before each compute phase (loads in flight across the phase).
// LDS layout: byte = buf*32768 + p*1024 + col*16 where p = kc*4 + g encodes
//   zn[colbase + s*64 + col][p*8 .. +8]  (kc*32 + g*8 == p*8).
__global__ __launch_bounds__(512, 2) void k_simsum(const unsigned short* __restrict__ zn,
                                                   float* __restrict__ partial) {
    __shared__ unsigned short lds[2][64 * DIM];   // 2 x 32 KB
    int bid = blockIdx.x;
    int rb = bid & 15;        // 16 row-blocks of 512
    int cc = bid >> 4;        // 32 col-chunks of 256
    int rowbase = rb * 512;
    int colbase = cc * 256;
    int tid = threadIdx.x, lane = tid & 63, w = tid >> 6;   // w in 0..7
    int cl = lane & 15, g = lane >> 4;

    // A fragments: lane holds zn[rowbase + w*64 + rt*16 + cl][kc*32 + g*8 .. +8]
    s16x8 afrag[4][8];
    #pragma unroll
    for (int rt = 0; rt < 4; ++rt) {
        int row = rowbase + w * 64 + rt * 16 + cl;
        const unsigned short* ap = zn + (size_t)row * DIM + g * 8;
        #pragma unroll
        for (int kc = 0; kc < 8; ++kc)
            afrag[rt][kc] = *(const s16x8*)(ap + kc * 32);
    }

    float pp[4][4];
    #pragma unroll
    for (int rt = 0; rt < 4; ++rt)
        #pragma unroll
        for (int r = 0; r < 4; ++r) pp[rt][r] = 0.0f;

    // stage 64 cols x 256 K into lds[buf]: each thread issues 4 x 16B;
    // wave w covers p = w*4 .. w*4+3 (p = kc*4+g), lane = col.
    auto stage = [&](int buf, int s) {
        const unsigned short* rowptr = zn + (size_t)(colbase + s * 64 + lane) * DIM;
        char* base = (char*)&lds[buf][0];
        #pragma unroll
        for (int j = 0; j < 4; ++j) {
            int p = w * 4 + j;
            gload_lds16(rowptr + p * 8, base + p * 1024);
        }
    };

    stage(0, 0);
    __syncthreads();   // prologue: buf0 ready

    for (int s = 0; s < 4; ++s) {
        int cur = s & 1;
        if (s < 3) stage(cur ^ 1, s + 1);   // issue next-tile loads BEFORE compute

        const char* lbase = (const char*)&lds[cur][0];
        #pragma unroll
        for (int ct = 0; ct < 4; ++ct) {
            f32x4 acc[4];
            #pragma unroll
            for (int rt = 0; rt < 4; ++rt) acc[rt] = (f32x4){0.f, 0.f, 0.f, 0.f};
            #pragma unroll
            for (int kc = 0; kc < 8; ++kc) {
                s16x8 bfrag = *(const s16x8*)(lbase + kc * 4096 + g * 1024 +
                                              (ct * 16 + cl) * 16);
                #pragma unroll
                for (int rt = 0; rt < 4; ++rt)
                    acc[rt] = __builtin_amdgcn_mfma_f32_16x16x32_bf16(
                                  afrag[rt][kc], bfrag, acc[rt], 0, 0, 0);
            }
            #pragma unroll
            for (int rt = 0; rt < 4; ++rt)
                #pragma unroll
                for (int r = 0; r < 4; ++r)
                    pp[rt][r] += __builtin_amdgcn_exp2f(acc[rt][r]);
        }
        __syncthreads();   // drains vmcnt (next buf staged) + lgkmcnt (cur reads done)
    }

    // reduce across the 16 col-lanes (cl) within each g-group
    #pragma unroll
    for (int rt = 0; rt < 4; ++rt) {
        #pragma unroll
        for (int r = 0; r < 4; ++r) {
            float v = pp[rt][r];
            v += __shfl_xor(v, 1);
            v += __shfl_xor(v, 2);
            v += __shfl_xor(v, 4);
            v += __shfl_xor(v, 8);
            if (cl == 0)
                partial[(size_t)cc * N2 + rowbase + w * 64 + rt * 16 + g * 4 + r] = v;
        }
    }
}

// ---- K3: per-row loss over 32 blocks; last block finishes the mean ----
__global__ __launch_bounds__(256) void k_loss(const float* __restrict__ partial,
                                              const float* __restrict__ diag,
                                              const float* __restrict__ posv,
                                              float* __restrict__ blocksum,
                                              unsigned int* __restrict__ counter,
                                              float* __restrict__ out) {
    int row = blockIdx.x * 256 + threadIdx.x;
    float sum = 0.0f;
    #pragma unroll
    for (int c = 0; c < 32; ++c) sum += partial[(size_t)c * N2 + row];
    sum -= __builtin_amdgcn_exp2f(diag[row]);           // remove diagonal term
    float lr = __builtin_amdgcn_logf(sum) * LN2 - posv[row & (BROWS - 1)];
    lr = wave_reduce(lr);
    __shared__ float red[4];
    if ((threadIdx.x & 63) == 0) red[threadIdx.x >> 6] = lr;
    __syncthreads();
    if (threadIdx.x == 0) {
        blocksum[blockIdx.x] = red[0] + red[1] + red[2] + red[3];
        __threadfence();                                  // publish blocksum
        unsigned int old = atomicAdd(counter, 1u);        // device-scope
        if (old == 31u) {                                 // last block finishes
            __threadfence();                              // acquire
            volatile const float* bs = blocksum;
            float t = 0.0f;
            for (int i = 0; i < 32; ++i) t += bs[i];
            out[0] = t * (1.0f / N2);
        }
    }
}

extern "C" void kernel_launch(void* const* d_in, const int* in_sizes, int n_in,
                              void* d_out, int out_size, void* d_ws, size_t ws_size,
                              hipStream_t stream) {
    const float* zi = (const float*)d_in[0];
    const float* zj = (const float*)d_in[1];
    float* out = (float*)d_out;

    char* ws = (char*)d_ws;
    unsigned short* zn    = (unsigned short*)ws;                       // 4 MB
    float* diag           = (float*)(ws + (4u << 20));                 // 32 KB
    float* posv           = (float*)(ws + (4u << 20) + (32u << 10));   // 16 KB
    float* blocksum       = (float*)(ws + (4u << 20) + (48u << 10));   // 128 B
    unsigned int* counter = (unsigned int*)(ws + (4u << 20) + (52u << 10));
    float* partial        = (float*)(ws + (4u << 20) + (64u << 10));   // 1 MB

    k_norm_pos<<<BROWS / 4, 256, 0, stream>>>(zi, zj, zn, diag, posv, counter);
    k_simsum<<<512, 512, 0, stream>>>(zn, partial);
    k_loss<<<32, 256, 0, stream>>>(partial, diag, posv, blocksum, counter, out);
}

// Round 9
// 74.840 us; speedup vs baseline: 1.2479x; 1.2479x over previous
//
#include <hip/hip_runtime.h>
#include <hip/hip_bf16.h>
#include <stdint.h>

// NT-Xent loss, B=4096, D=256, T=0.5, eps=1e-8.
// loss_r = log(sum_{c!=r} exp(2*dot(zn_r,zn_c))) - 2*dot(zin_r, zjn_r); out = mean.
// zn_s = zn * sqrt(2*log2e) stored FP8 E4M3 -> MFMA acc = 2*log2e*dot -> exp2(acc).
// Diagonal accumulated unconditionally; subtracted in k_loss via exp2(diag), where
// diag = sum(q(zn_s)^2) over the exact quantized fp8 values.
//
// LESSONS:
//  R2/R4: launch_bounds arg2>2 -> afrag spill -> 4-6x regression.
//  R6: no-LDS B loads can't pipeline in-regs -> L2-latency-bound.
//  R5/R7: bf16 zn (4MB) == XCD L2 size -> A-gather thrash at wider grids (FETCH 83MB).
//  R8: cvt_f32_fp8 selector must be a LITERAL -> manual unroll.

#define BROWS 4096
#define DIM   256
#define N2    8192

typedef __attribute__((ext_vector_type(4))) float f32x4;

#define S_EXP  1.6986436597467051f   /* sqrt(2*log2(e)) */
#define LN2    0.6931471805599453f

__device__ inline void gload_lds16(const void* g, void* l) {
    __builtin_amdgcn_global_load_lds(
        (const __attribute__((address_space(1))) uint32_t*)g,
        (__attribute__((address_space(3))) uint32_t*)l, 16, 0, 0);
}

__device__ inline float wave_reduce(float v) {
    #pragma unroll
    for (int m = 1; m < 64; m <<= 1) v += __shfl_xor(v, m);
    return v;
}

__device__ inline float fp8_selfdot4(int p) {
    float f0 = __builtin_amdgcn_cvt_f32_fp8(p, 0);
    float f1 = __builtin_amdgcn_cvt_f32_fp8(p, 1);
    float f2 = __builtin_amdgcn_cvt_f32_fp8(p, 2);
    float f3 = __builtin_amdgcn_cvt_f32_fp8(p, 3);
    return f0*f0 + f1*f1 + f2*f2 + f3*f3;
}

// ---- K1: fused normalize (both views) + positive-pair exponent + fp8 quantize ----
// One wave per pair i: writes fp8 rows i and i+4096 (4 B per lane), diag from the
// quantized values, posv in fp32. Also zeroes the k_loss completion counter.
__global__ __launch_bounds__(256) void k_norm_pos(const float* __restrict__ zi,
                                                  const float* __restrict__ zj,
                                                  uint8_t* __restrict__ zn,
                                                  float* __restrict__ diag,
                                                  float* __restrict__ posv,
                                                  unsigned int* __restrict__ counter) {
    if (blockIdx.x == 0 && threadIdx.x == 0) *counter = 0u;
    int i    = blockIdx.x * 4 + (threadIdx.x >> 6);
    int lane = threadIdx.x & 63;
    f32x4 a = *(const f32x4*)(zi + (size_t)i * DIM + lane * 4);
    f32x4 b = *(const f32x4*)(zj + (size_t)i * DIM + lane * 4);
    float ssa = a[0]*a[0] + a[1]*a[1] + a[2]*a[2] + a[3]*a[3];
    float ssb = b[0]*b[0] + b[1]*b[1] + b[2]*b[2] + b[3]*b[3];
    float dab = a[0]*b[0] + a[1]*b[1] + a[2]*b[2] + a[3]*b[3];
    ssa = wave_reduce(ssa);
    ssb = wave_reduce(ssb);
    dab = wave_reduce(dab);
    float na = 1.0f / fmaxf(sqrtf(ssa), 1e-8f);
    float nb = 1.0f / fmaxf(sqrtf(ssb), 1e-8f);
    if (lane == 0) posv[i] = 2.0f * dab * na * nb;   // natural-log exponent of pos pair

    float sa = na * S_EXP, sb = nb * S_EXP;
    // pack 4 scaled values to fp8 e4m3 (OCP) per row
    int pa = 0, pb = 0;
    pa = __builtin_amdgcn_cvt_pk_fp8_f32(a[0] * sa, a[1] * sa, pa, 0);
    pa = __builtin_amdgcn_cvt_pk_fp8_f32(a[2] * sa, a[3] * sa, pa, 1);
    pb = __builtin_amdgcn_cvt_pk_fp8_f32(b[0] * sb, b[1] * sb, pb, 0);
    pb = __builtin_amdgcn_cvt_pk_fp8_f32(b[2] * sb, b[3] * sb, pb, 1);
    *(uint32_t*)(zn + (size_t)i * DIM + lane * 4)           = (uint32_t)pa;
    *(uint32_t*)(zn + (size_t)(i + BROWS) * DIM + lane * 4) = (uint32_t)pb;

    // exact quantized self-dot for the diagonal correction (literal selectors)
    float da = fp8_selfdot4(pa);
    float db = fp8_selfdot4(pb);
    da = wave_reduce(da);
    db = wave_reduce(db);
    if (lane == 0) { diag[i] = da; diag[i + BROWS] = db; }
}

// ---- K2: fused sim GEMM (fp8) + exp2 + row-sum (diagonal NOT masked) ----
// 256 thr = 4 waves; block tile 256 rows x 256 cols; grid = 32*32 = 1024.
// Wave owns 64 rows: afrag[4][8] as i64 (64 VGPRs). B double-buffered in LDS
// 2 x 16 KB, staged BEFORE compute (loads in flight across the phase).
// LDS layout: byte = buf*16384 + kc*2048 + gp*1024 + col*16 + (g&1)*8 holds
//   zn[colbase + s*64 + col][kc*32 + g*8 .. +8]   (gp = g>>1)
__global__ __launch_bounds__(256, 2) void k_simsum(const uint8_t* __restrict__ zn,
                                                   float* __restrict__ partial) {
    __shared__ uint8_t lds[2][64 * DIM];   // 2 x 16 KB
    // bijective XCD swizzle (grid 1024, 8 XCDs -> 128 blocks per XCD chunk)
    int sw = (blockIdx.x & 7) * 128 + (blockIdx.x >> 3);
    int rb = sw & 31;         // 32 row-blocks of 256
    int cc = sw >> 5;         // 32 col-chunks of 256
    int rowbase = rb * 256;
    int colbase = cc * 256;
    int tid = threadIdx.x, lane = tid & 63, w = tid >> 6;   // w in 0..3
    int cl = lane & 15, g = lane >> 4;

    // A fragments: lane holds zn[rowbase + w*64 + rt*16 + cl][kc*32 + g*8 .. +8]
    long long afrag[4][8];
    #pragma unroll
    for (int rt = 0; rt < 4; ++rt) {
        int row = rowbase + w * 64 + rt * 16 + cl;
        const uint8_t* ap = zn + (size_t)row * DIM + g * 8;
        #pragma unroll
        for (int kc = 0; kc < 8; ++kc)
            afrag[rt][kc] = *(const long long*)(ap + kc * 32);
    }

    float pp[4][4];
    #pragma unroll
    for (int rt = 0; rt < 4; ++rt)
        #pragma unroll
        for (int r = 0; r < 4; ++r) pp[rt][r] = 0.0f;

    // stage 64 cols x 256 K (fp8) into lds[buf]: 256 thr x 16 B x 4 issues = 16 KB
    auto stage = [&](int buf, int s) {
        const uint8_t* rowptr = zn + (size_t)(colbase + s * 64 + lane) * DIM;
        char* base = (char*)&lds[buf][0];
        #pragma unroll
        for (int j = 0; j < 4; ++j) {
            int p = w * 4 + j;              // p = kc*2 + gp, p in 0..15
            gload_lds16(rowptr + (p >> 1) * 32 + (p & 1) * 16,
                        base + (p >> 1) * 2048 + (p & 1) * 1024);
        }
    };

    stage(0, 0);
    __syncthreads();   // prologue: buf0 ready

    for (int s = 0; s < 4; ++s) {
        int cur = s & 1;
        if (s < 3) stage(cur ^ 1, s + 1);   // issue next-tile loads BEFORE compute

        const char* lbase = (const char*)&lds[cur][0];
        #pragma unroll
        for (int ct = 0; ct < 4; ++ct) {
            f32x4 acc[4];
            #pragma unroll
            for (int rt = 0; rt < 4; ++rt) acc[rt] = (f32x4){0.f, 0.f, 0.f, 0.f};
            #pragma unroll
            for (int kc = 0; kc < 8; ++kc) {
                long long bfrag = *(const long long*)(lbase + kc * 2048 +
                                      (g >> 1) * 1024 + (ct * 16 + cl) * 16 +
                                      (g & 1) * 8);
                #pragma unroll
                for (int rt = 0; rt < 4; ++rt)
                    acc[rt] = __builtin_amdgcn_mfma_f32_16x16x32_fp8_fp8(
                                  afrag[rt][kc], bfrag, acc[rt], 0, 0, 0);
            }
            #pragma unroll
            for (int rt = 0; rt < 4; ++rt)
                #pragma unroll
                for (int r = 0; r < 4; ++r)
                    pp[rt][r] += __builtin_amdgcn_exp2f(acc[rt][r]);
        }
        __syncthreads();   // drains vmcnt (next buf staged) + lgkmcnt (cur reads done)
    }

    // reduce across the 16 col-lanes (cl) within each g-group
    #pragma unroll
    for (int rt = 0; rt < 4; ++rt) {
        #pragma unroll
        for (int r = 0; r < 4; ++r) {
            float v = pp[rt][r];
            v += __shfl_xor(v, 1);
            v += __shfl_xor(v, 2);
            v += __shfl_xor(v, 4);
            v += __shfl_xor(v, 8);
            if (cl == 0)
                partial[(size_t)cc * N2 + rowbase + w * 64 + rt * 16 + g * 4 + r] = v;
        }
    }
}

// ---- K3: per-row loss over 32 blocks; last block finishes the mean ----
__global__ __launch_bounds__(256) void k_loss(const float* __restrict__ partial,
                                              const float* __restrict__ diag,
                                              const float* __restrict__ posv,
                                              float* __restrict__ blocksum,
                                              unsigned int* __restrict__ counter,
                                              float* __restrict__ out) {
    int row = blockIdx.x * 256 + threadIdx.x;
    float sum = 0.0f;
    #pragma unroll
    for (int c = 0; c < 32; ++c) sum += partial[(size_t)c * N2 + row];
    sum -= __builtin_amdgcn_exp2f(diag[row]);           // remove diagonal term
    float lr = __builtin_amdgcn_logf(sum) * LN2 - posv[row & (BROWS - 1)];
    lr = wave_reduce(lr);
    __shared__ float red[4];
    if ((threadIdx.x & 63) == 0) red[threadIdx.x >> 6] = lr;
    __syncthreads();
    if (threadIdx.x == 0) {
        blocksum[blockIdx.x] = red[0] + red[1] + red[2] + red[3];
        __threadfence();                                  // publish blocksum
        unsigned int old = atomicAdd(counter, 1u);        // device-scope
        if (old == 31u) {                                 // last block finishes
            __threadfence();                              // acquire
            volatile const float* bs = blocksum;
            float t = 0.0f;
            for (int i = 0; i < 32; ++i) t += bs[i];
            out[0] = t * (1.0f / N2);
        }
    }
}

extern "C" void kernel_launch(void* const* d_in, const int* in_sizes, int n_in,
                              void* d_out, int out_size, void* d_ws, size_t ws_size,
                              hipStream_t stream) {
    const float* zi = (const float*)d_in[0];
    const float* zj = (const float*)d_in[1];
    float* out = (float*)d_out;

    char* ws = (char*)d_ws;
    uint8_t* zn           = (uint8_t*)ws;                              // 2 MB
    float* diag           = (float*)(ws + (2u << 20));                 // 32 KB
    float* posv           = (float*)(ws + (2u << 20) + (32u << 10));   // 16 KB
    float* blocksum       = (float*)(ws + (2u << 20) + (48u << 10));   // 128 B
    unsigned int* counter = (unsigned int*)(ws + (2u << 20) + (52u << 10));
    float* partial        = (float*)(ws + (2u << 20) + (64u << 10));   // 1 MB

    k_norm_pos<<<BROWS / 4, 256, 0, stream>>>(zi, zj, zn, diag, posv, counter);
    k_simsum<<<1024, 256, 0, stream>>>(zn, partial);
    k_loss<<<32, 256, 0, stream>>>(partial, diag, posv, blocksum, counter, out);
}

// Round 10
// 53.139 us; speedup vs baseline: 1.7575x; 1.4084x over previous
//
#include <hip/hip_runtime.h>
#include <hip/hip_bf16.h>
#include <stdint.h>

// NT-Xent loss, B=4096, D=256, T=0.5, eps=1e-8.
// loss_r = log(sum_{c!=r} exp(2*dot(zn_r,zn_c))) - 2*dot(zin_r, zjn_r); out = mean.
// zn_s = zn * sqrt(2*log2e) stored bf16 -> MFMA acc = 2*log2e*dot -> exp2(acc) direct.
// Diagonal accumulated unconditionally; subtracted in k_loss via exp2(diag), where
// diag = sum(zn_s_bf16^2) is the exact bf16 self-dot.
//
// LESSONS (R2..R9):
//  - launch_bounds arg2>2 or 512-thr blocks -> afrag spill -> 4-6x regression.
//  - grid>512 -> L2 thrash (FETCH 64-83MB) + scratch-class WRITE traffic.
//  - fp8 (R9): no win — spill-class traffic appeared; occupancy unchanged.
//  - Unified VGPR+AGPR footprint (~200+/wave) pins us at 2 waves/SIMD; accept it.
//  - R3 config is the proven-clean one: bf16, dbuf, grid 512, (256,2).

#define BROWS 4096
#define DIM   256
#define N2    8192

typedef __attribute__((ext_vector_type(4))) float          f32x4;
typedef __attribute__((ext_vector_type(8))) short          s16x8;
typedef __attribute__((ext_vector_type(4))) unsigned short u16x4;

#define S_EXP  1.6986436597467051f   /* sqrt(2*log2(e)) */
#define LN2    0.6931471805599453f

__device__ inline unsigned short f2bf(float f) {
    uint32_t b = __float_as_uint(f);
    b += 0x7fffu + ((b >> 16) & 1u);   // RNE
    return (unsigned short)(b >> 16);
}
__device__ inline float bf2f(unsigned short u) {
    return __uint_as_float(((uint32_t)u) << 16);
}

__device__ inline void gload_lds16(const void* g, void* l) {
    __builtin_amdgcn_global_load_lds(
        (const __attribute__((address_space(1))) uint32_t*)g,
        (__attribute__((address_space(3))) uint32_t*)l, 16, 0, 0);
}

__device__ inline float wave_reduce(float v) {
    #pragma unroll
    for (int m = 1; m < 64; m <<= 1) v += __shfl_xor(v, m);
    return v;
}

// ---- K1: fused normalize (both views) + positive-pair exponent + diag self-dot ----
// Also zeroes the completion counter used by k_loss's last-block finish.
__global__ __launch_bounds__(256) void k_norm_pos(const float* __restrict__ zi,
                                                  const float* __restrict__ zj,
                                                  unsigned short* __restrict__ zn,
                                                  float* __restrict__ diag,
                                                  float* __restrict__ posv,
                                                  unsigned int* __restrict__ counter) {
    if (blockIdx.x == 0 && threadIdx.x == 0) *counter = 0u;
    int i    = blockIdx.x * 4 + (threadIdx.x >> 6);
    int lane = threadIdx.x & 63;
    f32x4 a = *(const f32x4*)(zi + (size_t)i * DIM + lane * 4);
    f32x4 b = *(const f32x4*)(zj + (size_t)i * DIM + lane * 4);
    float ssa = a[0]*a[0] + a[1]*a[1] + a[2]*a[2] + a[3]*a[3];
    float ssb = b[0]*b[0] + b[1]*b[1] + b[2]*b[2] + b[3]*b[3];
    float dab = a[0]*b[0] + a[1]*b[1] + a[2]*b[2] + a[3]*b[3];
    ssa = wave_reduce(ssa);
    ssb = wave_reduce(ssb);
    dab = wave_reduce(dab);
    float na = 1.0f / fmaxf(sqrtf(ssa), 1e-8f);
    float nb = 1.0f / fmaxf(sqrtf(ssb), 1e-8f);
    if (lane == 0) posv[i] = 2.0f * dab * na * nb;   // natural-log exponent of pos pair

    float sa = na * S_EXP, sb = nb * S_EXP;
    u16x4 oa, ob;
    float da = 0.0f, db = 0.0f;
    #pragma unroll
    for (int k = 0; k < 4; ++k) {
        unsigned short ua = f2bf(a[k] * sa);
        unsigned short ub = f2bf(b[k] * sb);
        oa[k] = ua; ob[k] = ub;
        float fa = bf2f(ua), fb = bf2f(ub);
        da += fa * fa; db += fb * fb;
    }
    *(u16x4*)(zn + (size_t)i * DIM + lane * 4)           = oa;
    *(u16x4*)(zn + (size_t)(i + BROWS) * DIM + lane * 4) = ob;
    da = wave_reduce(da);
    db = wave_reduce(db);
    if (lane == 0) { diag[i] = da; diag[i + BROWS] = db; }
}

// ---- K2: fused sim GEMM + exp2 + row-sum (diagonal NOT masked) — exact R3 ----
// 256 thr = 4 waves; 256 rows x 512 cols per block; grid = 32*16 = 512.
// Wave owns 64 rows (4 row-tiles of 16), A-frags pinned (128 VGPR, K=256).
// Double-buffered LDS (2x32KB), next tile staged BEFORE compute phase.
// LDS layout: byte = buf*32768 + kc*4096 + g*1024 + col*16
//   holds zn[colbase + s*64 + col][kc*32 + g*8 .. +8]
__global__ __launch_bounds__(256, 2) void k_simsum(const unsigned short* __restrict__ zn,
                                                   float* __restrict__ partial) {
    __shared__ unsigned short lds[2][64 * DIM];   // 2 x 32 KB
    int bid = blockIdx.x;
    int rb = bid & 31;        // 32 row-blocks of 256
    int cc = bid >> 5;        // 16 col-chunks of 512
    int rowbase = rb * 256;
    int colbase = cc * 512;
    int tid = threadIdx.x, lane = tid & 63, w = tid >> 6;   // w in 0..3
    int cl = lane & 15, g = lane >> 4;

    // A fragments: lane holds zn[rowbase + w*64 + rt*16 + cl][kc*32 + g*8 .. +8]
    s16x8 afrag[4][8];
    #pragma unroll
    for (int rt = 0; rt < 4; ++rt) {
        int row = rowbase + w * 64 + rt * 16 + cl;
        const unsigned short* ap = zn + (size_t)row * DIM + g * 8;
        #pragma unroll
        for (int kc = 0; kc < 8; ++kc)
            afrag[rt][kc] = *(const s16x8*)(ap + kc * 32);
    }

    float pp[4][4];
    #pragma unroll
    for (int rt = 0; rt < 4; ++rt)
        #pragma unroll
        for (int r = 0; r < 4; ++r) pp[rt][r] = 0.0f;

    // stage 64 cols x 256 K into lds[buf]; 256 lanes x 16 B x 8 issues = 32 KB
    auto stage = [&](int buf, int s) {
        int crow = colbase + s * 64 + lane;
        const unsigned short* gsrc = zn + (size_t)crow * DIM;
        char* base = (char*)&lds[buf][0];
        #pragma unroll
        for (int i = 0; i < 8; ++i)
            gload_lds16(gsrc + i * 32 + w * 8, base + i * 4096 + w * 1024);
    };

    stage(0, 0);
    __syncthreads();   // prologue: buf0 ready

    for (int s = 0; s < 8; ++s) {
        int cur = s & 1;
        if (s < 7) stage(cur ^ 1, s + 1);   // issue next-tile loads BEFORE compute

        const char* lbase = (const char*)&lds[cur][0];
        #pragma unroll
        for (int ct = 0; ct < 4; ++ct) {
            f32x4 acc[4];
            #pragma unroll
            for (int rt = 0; rt < 4; ++rt) acc[rt] = (f32x4){0.f, 0.f, 0.f, 0.f};
            #pragma unroll
            for (int kc = 0; kc < 8; ++kc) {
                s16x8 bfrag = *(const s16x8*)(lbase + kc * 4096 + g * 1024 +
                                              (ct * 16 + cl) * 16);
                #pragma unroll
                for (int rt = 0; rt < 4; ++rt)
                    acc[rt] = __builtin_amdgcn_mfma_f32_16x16x32_bf16(
                                  afrag[rt][kc], bfrag, acc[rt], 0, 0, 0);
            }
            #pragma unroll
            for (int rt = 0; rt < 4; ++rt)
                #pragma unroll
                for (int r = 0; r < 4; ++r)
                    pp[rt][r] += __builtin_amdgcn_exp2f(acc[rt][r]);
        }
        __syncthreads();   // drains vmcnt (next buf staged) + lgkmcnt (cur reads done)
    }

    // reduce across the 16 col-lanes (cl) within each g-group
    #pragma unroll
    for (int rt = 0; rt < 4; ++rt) {
        #pragma unroll
        for (int r = 0; r < 4; ++r) {
            float v = pp[rt][r];
            v += __shfl_xor(v, 1);
            v += __shfl_xor(v, 2);
            v += __shfl_xor(v, 4);
            v += __shfl_xor(v, 8);
            if (cl == 0)
                partial[(size_t)cc * N2 + rowbase + w * 64 + rt * 16 + g * 4 + r] = v;
        }
    }
}

// ---- K3: per-row loss over 32 blocks; last block finishes the mean ----
__global__ __launch_bounds__(256) void k_loss(const float* __restrict__ partial,
                                              const float* __restrict__ diag,
                                              const float* __restrict__ posv,
                                              float* __restrict__ blocksum,
                                              unsigned int* __restrict__ counter,
                                              float* __restrict__ out) {
    int row = blockIdx.x * 256 + threadIdx.x;
    float sum = 0.0f;
    #pragma unroll
    for (int c = 0; c < 16; ++c) sum += partial[(size_t)c * N2 + row];
    sum -= __builtin_amdgcn_exp2f(diag[row]);           // remove diagonal term
    float lr = __builtin_amdgcn_logf(sum) * LN2 - posv[row & (BROWS - 1)];
    lr = wave_reduce(lr);
    __shared__ float red[4];
    if ((threadIdx.x & 63) == 0) red[threadIdx.x >> 6] = lr;
    __syncthreads();
    if (threadIdx.x == 0) {
        blocksum[blockIdx.x] = red[0] + red[1] + red[2] + red[3];
        __threadfence();                                  // publish blocksum
        unsigned int old = atomicAdd(counter, 1u);        // device-scope
        if (old == 31u) {                                 // last block finishes
            __threadfence();                              // acquire
            volatile const float* bs = blocksum;
            float t = 0.0f;
            for (int i = 0; i < 32; ++i) t += bs[i];
            out[0] = t * (1.0f / N2);
        }
    }
}

extern "C" void kernel_launch(void* const* d_in, const int* in_sizes, int n_in,
                              void* d_out, int out_size, void* d_ws, size_t ws_size,
                              hipStream_t stream) {
    const float* zi = (const float*)d_in[0];
    const float* zj = (const float*)d_in[1];
    float* out = (float*)d_out;

    char* ws = (char*)d_ws;
    unsigned short* zn    = (unsigned short*)ws;                       // 4 MB
    float* diag           = (float*)(ws + (4u << 20));                 // 32 KB
    float* posv           = (float*)(ws + (4u << 20) + (32u << 10));   // 16 KB
    float* blocksum       = (float*)(ws + (4u << 20) + (48u << 10));   // 128 B
    unsigned int* counter = (unsigned int*)(ws + (4u << 20) + (52u << 10));
    float* partial        = (float*)(ws + (4u << 20) + (64u << 10));   // 512 KB

    k_norm_pos<<<BROWS / 4, 256, 0, stream>>>(zi, zj, zn, diag, posv, counter);
    k_simsum<<<512, 256, 0, stream>>>(zn, partial);
    k_loss<<<32, 256, 0, stream>>>(partial, diag, posv, blocksum, counter, out);
}